// Round 5
// baseline (1849.238 us; speedup 1.0000x reference)
//
#include <hip/hip_runtime.h>
#include <math.h>
#include <stdint.h>

// VQ-VAE vector quantizer (inference), MI355X / gfx950.
// N=32768 tokens, D=256, K=8192 codes. f32 (no fp32 MFMA on CDNA4).
// Reference rounding replicated exactly: d = fl(fl(S+e2) - 2*dot), fmaf chain
// over d ascending, argmin first-index. absmax=0.0 through round 4.
// Round-5: (1) z read straight from global (row-major float4; 16-way
// same-address lanes HW-merge; L1/L2-hot) -> z leaves LDS entirely, LDS instr
// floor 983->655us. (2) v_pk_fma_f32 pairs j: 64 pk + 16 movs vs 128 FMA
// -> VALU floor 874->546us, acc pinned to arch VGPRs by the asm constraint.

#define N_TOK   32768
#define DIM     256
#define K_EMB   8192

// ---- workspace layout (bytes) ----
#define WS_S       0          // float[32768]
#define WS_E2      131072     // float[8192]
#define WS_PVAL    163840     // float[2*32768]
#define WS_PIDX    425984     // int[2*32768]
#define WS_CNT     688128     // float[8192]
#define WS_PART    720896     // float[32768]
#define WS_ET      851968     // float[8192*256] E^T for k_out gather (optional)
#define WS_END_ET  9240576

typedef __attribute__((ext_vector_type(2))) float f32x2;

__device__ __forceinline__ void pk_fma(f32x2& a, f32x2 x, f32x2 y) {
  // 2 independent IEEE FMAs per lane; same rounding as fmaf -> chain preserved
  asm("v_pk_fma_f32 %0, %1, %2, %0" : "+v"(a) : "v"(x), "v"(y));
}

__device__ __forceinline__ void gload_lds16(const float* g, float* l) {
  __builtin_amdgcn_global_load_lds(
      (const __attribute__((address_space(1))) void*)g,
      (__attribute__((address_space(3))) void*)l, 16, 0, 0);
}

__global__ void k_sumz(const float* __restrict__ z, float* __restrict__ S) {
  int t = blockIdx.x * blockDim.x + threadIdx.x;
  const float4* zp = (const float4*)(z + (size_t)t * DIM);
  float s = 0.0f;
  #pragma unroll 4
  for (int g = 0; g < DIM / 4; ++g) {
    float4 v = zp[g];
    s = __fadd_rn(s, __fmul_rn(v.x, v.x));
    s = __fadd_rn(s, __fmul_rn(v.y, v.y));
    s = __fadd_rn(s, __fmul_rn(v.z, v.z));
    s = __fadd_rn(s, __fmul_rn(v.w, v.w));
  }
  S[t] = s;
}

// e2 exact value non-critical: fl(S+e2)==S (S~256, e2<4e-6).
__global__ void k_sume(const float* __restrict__ E, float* __restrict__ e2) {
  __shared__ float part[4][64];
  int c  = threadIdx.x & 63;
  int dq = threadIdx.x >> 6;
  int col = blockIdx.x * 64 + c;
  float s = 0.0f;
  #pragma unroll 4
  for (int d = dq * 64; d < dq * 64 + 64; ++d) {
    float v = E[(size_t)d * K_EMB + col];
    s = __fadd_rn(s, __fmul_rn(v, v));
  }
  part[dq][c] = s;
  __syncthreads();
  if (threadIdx.x < 64)
    e2[blockIdx.x * 64 + threadIdx.x] =
        __fadd_rn(__fadd_rn(part[0][threadIdx.x], part[1][threadIdx.x]),
                  __fadd_rn(part[2][threadIdx.x], part[3][threadIdx.x]));
}

// E[256][8192] -> ET[8192][256] for k_out's coalesced row gather.
__global__ void k_transpose_e(const float* __restrict__ E, float* __restrict__ ET) {
  __shared__ float tile[32][33];
  int k0 = blockIdx.x * 32, d0 = blockIdx.y * 32;
  int lx = threadIdx.x, ly = threadIdx.y;  // 32 x 8
  #pragma unroll
  for (int r = 0; r < 32; r += 8)
    tile[ly + r][lx] = E[(size_t)(d0 + ly + r) * K_EMB + k0 + lx];
  __syncthreads();
  #pragma unroll
  for (int r = 0; r < 32; r += 8)
    ET[(size_t)(k0 + ly + r) * DIM + d0 + lx] = tile[lx][ly + r];
}

// ---- fused distance-GEMM + argmin ----
// 8x16 per-thread tile (acc as 8x8 f32x2). E staged in LDS (32KB dbuf) via
// global_load_lds; z read from global per 4-d chunk. Per CU (2 blocks,
// 8 waves): LDS = 4 b128/wave-d (E only) -> 655us floor; pk-VALU ~546us.
#define BM 128
#define BN 256
#define BK 16
#define KSTEPS 16
#define NCT 16                   // 16 col-tiles x 256 = 4096 cols (half of K)
#define NSTEP (NCT * KSTEPS)     // 256

__launch_bounds__(256, 2)
__global__ void k_dist(const float* __restrict__ z, const float* __restrict__ E,
                       const float* __restrict__ S, const float* __restrict__ e2,
                       float* __restrict__ pval, int* __restrict__ pidx) {
  __shared__ __align__(16) float smem[2 * BK * BN];  // 32 KB: E tiles only
  float* et = smem;

  const int tid = threadIdx.x;
  const int tx  = tid & 15;     // col group
  const int ty  = tid >> 4;     // row group
  const int wv  = tid >> 6;
  const int ln  = tid & 63;
  const int rowblk = blockIdx.x >> 1;
  const int half   = blockIdx.x & 1;
  const int row0    = rowblk * BM;
  const int colbase = half * (NCT * BN);

  f32x2 acc[8][8];
  #pragma unroll
  for (int i = 0; i < 8; ++i)
    #pragma unroll
    for (int jp = 0; jp < 8; ++jp) acc[i][jp] = (f32x2){0.0f, 0.0f};

  float best[8];
  int   bidx[8];
  #pragma unroll
  for (int i = 0; i < 8; ++i) { best[i] = 3.402823466e38f; bidx[i] = 0; }

  // this thread's 8 z-rows (global, row-major)
  const float* zrow[8];
  float Sreg[8];
  #pragma unroll
  for (int i = 0; i < 8; ++i) {
    int r = row0 + (i >> 2) * 64 + ty * 4 + (i & 3);
    zrow[i] = z + (size_t)r * DIM;
    Sreg[i] = S[r];
  }

  // E tile: 16 d-rows x 1KB; wave wv stages d-rows {wv,4+wv,8+wv,12+wv}
  auto LOADE = [&](int gs) {
    int ks = gs & (KSTEPS - 1), ct = gs >> 4;
    const float* gsrc = E + (size_t)(ks * BK) * K_EMB + colbase + ct * BN + ln * 4;
    float* lb = et + (gs & 1) * (BK * BN);
    #pragma unroll
    for (int it = 0; it < 4; ++it) {
      int dd = it * 4 + wv;
      gload_lds16(gsrc + (size_t)dd * K_EMB, lb + dd * BN);
    }
  };

  LOADE(0);
  __syncthreads();  // drains vmcnt -> E tile 0 resident

  for (int gs = 0; gs < NSTEP; ++gs) {
    const int buf = gs & 1;
    if (gs + 1 < NSTEP) LOADE(gs + 1);  // writes buf^1 (read-finished 1 barrier ago)

    const float* eb = et + buf * (BK * BN);
    const int d0 = (gs & (KSTEPS - 1)) * BK;

    #pragma unroll
    for (int dq = 0; dq < 4; ++dq) {      // 4 d's per chunk
      float4 zv[8];
      #pragma unroll
      for (int i = 0; i < 8; ++i)         // 16 same-addr lanes merge in L1/L2
        zv[i] = *(const float4*)(zrow[i] + d0 + dq * 4);
      #pragma unroll
      for (int t = 0; t < 4; ++t) {       // d = d0 + dq*4 + t, ascending
        int d = dq * 4 + t;
        f32x2 ep[8];
        #pragma unroll
        for (int g = 0; g < 4; ++g) {
          float4 w = *(const float4*)&eb[d * BN + g * 64 + tx * 4];
          ep[2 * g + 0] = (f32x2){w.x, w.y};
          ep[2 * g + 1] = (f32x2){w.z, w.w};
        }
        #pragma unroll
        for (int i = 0; i < 8; ++i) {
          float zs = (t == 0) ? zv[i].x : (t == 1) ? zv[i].y
                   : (t == 2) ? zv[i].z : zv[i].w;
          f32x2 zp = (f32x2){zs, zs};
          #pragma unroll
          for (int jp = 0; jp < 8; ++jp) pk_fma(acc[i][jp], zp, ep[jp]);
        }
      }
    }

    // per col-tile: reference-exact d = fl(fl(S+e2) - 2*dot), strict-< argmin
    if ((gs & (KSTEPS - 1)) == KSTEPS - 1) {
      int col0c = colbase + (gs >> 4) * BN;
      float e2r[16];
      #pragma unroll
      for (int j = 0; j < 16; ++j)
        e2r[j] = e2[col0c + (j >> 2) * 64 + tx * 4 + (j & 3)];
      #pragma unroll
      for (int i = 0; i < 8; ++i) {
        #pragma unroll
        for (int j = 0; j < 16; ++j) {  // j ascending == index ascending
          float dotv = acc[i][j >> 1][j & 1];
          float t1   = __fadd_rn(Sreg[i], e2r[j]);
          float val  = __fsub_rn(t1, __fmul_rn(2.0f, dotv));
          int cidx   = col0c + (j >> 2) * 64 + tx * 4 + (j & 3);
          if (val < best[i]) { best[i] = val; bidx[i] = cidx; }
          acc[i][j >> 1][j & 1] = 0.0f;
        }
      }
    }

    __syncthreads();  // one barrier/gs: E-prefetch landed, buffers ordered
  }

  // per-row argmin across 16 tx candidates, lexicographic (val, idx)
  float* redv = smem;
  int*   redi = (int*)(smem + BM * 16);
  #pragma unroll
  for (int i = 0; i < 8; ++i) {
    int r = (i >> 2) * 64 + ty * 4 + (i & 3);
    redv[r * 16 + tx] = best[i];
    redi[r * 16 + tx] = bidx[i];
  }
  __syncthreads();
  if (tid < BM) {
    float bv = redv[tid * 16];
    int   bi = redi[tid * 16];
    #pragma unroll
    for (int u = 1; u < 16; ++u) {
      float v = redv[tid * 16 + u];
      int  ii = redi[tid * 16 + u];
      if (v < bv || (v == bv && ii < bi)) { bv = v; bi = ii; }
    }
    pval[(size_t)half * N_TOK + row0 + tid] = bv;
    pidx[(size_t)half * N_TOK + row0 + tid] = bi;
  }
}

__global__ void k_out(const float* __restrict__ z, const float* __restrict__ E,
                      const float* __restrict__ ET, int useET,
                      const float* __restrict__ pval, const int* __restrict__ pidx,
                      float* __restrict__ out, float* __restrict__ counts,
                      float* __restrict__ partials) {
  int n = blockIdx.x;
  int t = threadIdx.x;
  float bv = pval[n];
  int   bi = pidx[n];
  {  // half 1 (indices all larger; strict < keeps lowest)
    float v = pval[(size_t)N_TOK + n];
    int  ii = pidx[(size_t)N_TOK + n];
    if (v < bv || (v == bv && ii < bi)) { bv = v; bi = ii; }
  }
  int idx = bi;

  float q  = useET ? ET[(size_t)idx * DIM + t]
                   : E[(size_t)t * K_EMB + idx];
  float zz = z[(size_t)n * DIM + t];
  float dd = __fsub_rn(q, zz);
  out[(size_t)n * DIM + t] = __fadd_rn(zz, dd);  // straight-through: z + (q - z)
  float sq = __fmul_rn(dd, dd);

  #pragma unroll
  for (int o = 32; o > 0; o >>= 1) sq += __shfl_down(sq, o);
  __shared__ float wsum[4];
  if ((t & 63) == 0) wsum[t >> 6] = sq;
  __syncthreads();
  if (t == 0) {
    partials[n] = ((wsum[0] + wsum[1]) + (wsum[2] + wsum[3]));
    atomicAdd(&counts[idx], 1.0f);
    out[(size_t)N_TOK * DIM + n] = (float)idx;
  }
}

__global__ void k_final(const float* __restrict__ partials,
                        const float* __restrict__ counts,
                        float* __restrict__ out) {
  __shared__ double sd[256];
  int t = threadIdx.x;
  double s = 0.0;
  for (int i = t; i < N_TOK; i += 256) s += (double)partials[i];
  sd[t] = s;
  __syncthreads();
  for (int o = 128; o > 0; o >>= 1) { if (t < o) sd[t] += sd[t + o]; __syncthreads(); }
  double totalLoss = sd[0];
  __syncthreads();
  double s2 = 0.0;
  for (int k = t; k < K_EMB; k += 256) {
    float p = counts[k] * (1.0f / (float)N_TOK);
    s2 += (double)(p * logf(p + 1e-10f));
  }
  sd[t] = s2;
  __syncthreads();
  for (int o = 128; o > 0; o >>= 1) { if (t < o) sd[t] += sd[t + o]; __syncthreads(); }
  if (t == 0) {
    const size_t base = (size_t)N_TOK * DIM + N_TOK;  // 8421376
    out[base + 0] = 0.0f;
    out[base + 1] = 0.25f * (float)(totalLoss / (double)(N_TOK * DIM));
    out[base + 2] = expf(-(float)sd[0]);
  }
}

extern "C" void kernel_launch(void* const* d_in, const int* in_sizes, int n_in,
                              void* d_out, int out_size, void* d_ws, size_t ws_size,
                              hipStream_t stream) {
  const float* z = (const float*)d_in[0];
  const float* E = (const float*)d_in[1];
  float* out = (float*)d_out;
  char* w = (char*)d_ws;
  float* S        = (float*)(w + WS_S);
  float* e2       = (float*)(w + WS_E2);
  float* pval     = (float*)(w + WS_PVAL);
  int*   pidx     = (int*)(w + WS_PIDX);
  float* counts   = (float*)(w + WS_CNT);
  float* partials = (float*)(w + WS_PART);
  float* ET       = (float*)(w + WS_ET);
  const int useET = (ws_size >= (size_t)WS_END_ET) ? 1 : 0;  // constant across calls

  hipMemsetAsync(w + WS_CNT, 0, K_EMB * sizeof(float), stream);
  k_sumz<<<N_TOK / 256, 256, 0, stream>>>(z, S);
  k_sume<<<K_EMB / 64, 256, 0, stream>>>(E, e2);
  if (useET)
    k_transpose_e<<<dim3(K_EMB / 32, DIM / 32), dim3(32, 8), 0, stream>>>(E, ET);
  k_dist<<<512, 256, 0, stream>>>(z, E, S, e2, pval, pidx);
  k_out<<<N_TOK, 256, 0, stream>>>(z, E, ET, useET, pval, pidx, out, counts, partials);
  k_final<<<1, 256, 0, stream>>>(partials, counts, out);
}

// Round 6
// 1635.227 us; speedup vs baseline: 1.1309x; 1.1309x over previous
//
#include <hip/hip_runtime.h>
#include <math.h>
#include <stdint.h>

// VQ-VAE vector quantizer (inference), MI355X / gfx950.
// N=32768 tokens, D=256, K=8192 codes. f32 (no fp32 MFMA on CDNA4; bf16 MFMA
// would flip ulp-binned argmin ties -> absmax>=1 on index output. VALU only.)
// Reference rounding replicated exactly: d = fl(fl(S+e2) - 2*dot), fmaf chain
// over d ascending, argmin first-index. absmax=0.0 through round 5.
//
// Round-6: round-4 structure (1695us, z+E LDS, gload_lds staging) with ONE
// change: inner loop uses v_pk_fma_f32 + op_sel broadcast (no dup movs, no
// asm-forced operand copies). Round-5 failed (1876us, VGPR=128) because
// pinned acc pairs + 48 extra transient regs (zv/zrow) forced AGPR traffic;
// here transients are 24 regs and z stays in LDS -> ~195 live, no AGPR moves.

#define N_TOK   32768
#define DIM     256
#define K_EMB   8192

// ---- workspace layout (bytes) ----
#define WS_S       0          // float[32768]
#define WS_E2      131072     // float[8192]
#define WS_PVAL    163840     // float[2*32768]
#define WS_PIDX    425984     // int[2*32768]
#define WS_CNT     688128     // float[8192]
#define WS_PART    720896     // float[32768]
#define WS_ZT      851968     // float[256*32768] z transposed
#define WS_END_ZT  34406400
#define WS_ET      34406400   // float[8192*256]  E transposed (k_out gather)
#define WS_END_ET  42795008

typedef __attribute__((ext_vector_type(2))) float f32x2;

// acc.lo += z.lo*e.lo ; acc.hi += z.lo*e.hi   (broadcast LOW half of src0)
__device__ __forceinline__ void pk_fma_blo(f32x2& a, f32x2 z, f32x2 e) {
  asm("v_pk_fma_f32 %0, %1, %2, %0 op_sel:[0,0,0] op_sel_hi:[0,1,1]"
      : "+v"(a) : "v"(z), "v"(e));
}
// acc.lo += z.hi*e.lo ; acc.hi += z.hi*e.hi   (broadcast HIGH half of src0)
__device__ __forceinline__ void pk_fma_bhi(f32x2& a, f32x2 z, f32x2 e) {
  asm("v_pk_fma_f32 %0, %1, %2, %0 op_sel:[1,0,0] op_sel_hi:[1,1,1]"
      : "+v"(a) : "v"(z), "v"(e));
}

__device__ __forceinline__ void gload_lds16(const float* g, float* l) {
  __builtin_amdgcn_global_load_lds(
      (const __attribute__((address_space(1))) void*)g,
      (__attribute__((address_space(3))) void*)l, 16, 0, 0);
}

__global__ void k_sumz(const float* __restrict__ z, float* __restrict__ S) {
  int t = blockIdx.x * blockDim.x + threadIdx.x;
  const float4* zp = (const float4*)(z + (size_t)t * DIM);
  float s = 0.0f;
  #pragma unroll 4
  for (int g = 0; g < DIM / 4; ++g) {
    float4 v = zp[g];
    s = __fadd_rn(s, __fmul_rn(v.x, v.x));
    s = __fadd_rn(s, __fmul_rn(v.y, v.y));
    s = __fadd_rn(s, __fmul_rn(v.z, v.z));
    s = __fadd_rn(s, __fmul_rn(v.w, v.w));
  }
  S[t] = s;
}

// e2 exact value non-critical: fl(S+e2)==S (S~256, e2<4e-6).
__global__ void k_sume(const float* __restrict__ E, float* __restrict__ e2) {
  __shared__ float part[4][64];
  int c  = threadIdx.x & 63;
  int dq = threadIdx.x >> 6;
  int col = blockIdx.x * 64 + c;
  float s = 0.0f;
  #pragma unroll 4
  for (int d = dq * 64; d < dq * 64 + 64; ++d) {
    float v = E[(size_t)d * K_EMB + col];
    s = __fadd_rn(s, __fmul_rn(v, v));
  }
  part[dq][c] = s;
  __syncthreads();
  if (threadIdx.x < 64)
    e2[blockIdx.x * 64 + threadIdx.x] =
        __fadd_rn(__fadd_rn(part[0][threadIdx.x], part[1][threadIdx.x]),
                  __fadd_rn(part[2][threadIdx.x], part[3][threadIdx.x]));
}

// z[32768][256] -> zT[256][32768], 32x32 tiles, +1-pad LDS. ~15us.
__global__ void k_transpose_z(const float* __restrict__ z, float* __restrict__ zT) {
  __shared__ float tile[32][33];
  int n0 = blockIdx.x * 32, d0 = blockIdx.y * 32;
  int lx = threadIdx.x, ly = threadIdx.y;  // 32 x 8
  #pragma unroll
  for (int r = 0; r < 32; r += 8)
    tile[ly + r][lx] = z[(size_t)(n0 + ly + r) * DIM + d0 + lx];
  __syncthreads();
  #pragma unroll
  for (int r = 0; r < 32; r += 8)
    zT[(size_t)(d0 + ly + r) * N_TOK + n0 + lx] = tile[lx][ly + r];
}

// E[256][8192] -> ET[8192][256] for k_out's coalesced row gather.
__global__ void k_transpose_e(const float* __restrict__ E, float* __restrict__ ET) {
  __shared__ float tile[32][33];
  int k0 = blockIdx.x * 32, d0 = blockIdx.y * 32;
  int lx = threadIdx.x, ly = threadIdx.y;
  #pragma unroll
  for (int r = 0; r < 32; r += 8)
    tile[ly + r][lx] = E[(size_t)(d0 + ly + r) * K_EMB + k0 + lx];
  __syncthreads();
  #pragma unroll
  for (int r = 0; r < 32; r += 8)
    ET[(size_t)(k0 + ly + r) * DIM + d0 + lx] = tile[lx][ly + r];
}

// ---- fused distance-GEMM + argmin ----
// 8x16 per-thread tile as f32x2 acc[8][8]. BM=128, BN=256, BK=16, 48KB LDS
// double-buffered, both operands staged via global_load_lds, 2 blocks/CU.
// Per d per thread: 6 b128 LDS reads + 64 pk-FMA (0 movs via op_sel).
#define BM 128
#define BN 256
#define BK 16
#define KSTEPS 16
#define NCT 16                   // 16 col-tiles x 256 = 4096 cols (half of K)
#define NSTEP (NCT * KSTEPS)     // 256

template<bool USE_ZT>
__launch_bounds__(256, 2)
__global__ void k_dist(const float* __restrict__ zsrc, const float* __restrict__ E,
                       const float* __restrict__ S, const float* __restrict__ e2,
                       float* __restrict__ pval, int* __restrict__ pidx) {
  __shared__ __align__(16) float smem[2 * BK * BM + 2 * BK * BN];  // 48 KB
  float* zt = smem;
  float* et = smem + 2 * BK * BM;

  const int tid = threadIdx.x;
  const int tx  = tid & 15;     // col group
  const int ty  = tid >> 4;     // row group
  const int wv  = tid >> 6;
  const int ln  = tid & 63;
  const int rowblk = blockIdx.x >> 1;
  const int half   = blockIdx.x & 1;
  const int row0    = rowblk * BM;
  const int colbase = half * (NCT * BN);

  f32x2 acc[8][8];   // acc[i][jp] = row i, cols (2jp, 2jp+1) of the 16-col strip
  #pragma unroll
  for (int i = 0; i < 8; ++i)
    #pragma unroll
    for (int jp = 0; jp < 8; ++jp) acc[i][jp] = (f32x2){0.0f, 0.0f};

  float best[8];
  int   bidx[8];
  #pragma unroll
  for (int i = 0; i < 8; ++i) { best[i] = 3.402823466e38f; bidx[i] = 0; }

  float Sreg[8];
  #pragma unroll
  for (int i = 0; i < 8; ++i)
    Sreg[i] = S[row0 + (i >> 2) * 64 + ty * 4 + (i & 3)];

  // E tile: 16 d-rows x 1KB; wave wv stages d-rows {wv,4+wv,8+wv,12+wv}
  auto LOADE = [&](int gs) {
    int ks = gs & (KSTEPS - 1), ct = gs >> 4;
    const float* gsrc = E + (size_t)(ks * BK) * K_EMB + colbase + ct * BN + ln * 4;
    float* lb = et + (gs & 1) * (BK * BN);
    #pragma unroll
    for (int it = 0; it < 4; ++it) {
      int dd = it * 4 + wv;
      gload_lds16(gsrc + (size_t)dd * K_EMB, lb + dd * BN);
    }
  };
  // zT tile: 16 d-rows x 512B; one 1KB wave-instr covers a d-row PAIR
  auto LOADZT = [&](int gs) {
    int d0 = (gs & (KSTEPS - 1)) * BK;
    float* lb = zt + (gs & 1) * (BK * BM);
    int h = ln >> 5, j = ln & 31;
    #pragma unroll
    for (int it = 0; it < 2; ++it) {
      int p = it * 4 + wv;
      gload_lds16(zsrc + (size_t)(d0 + 2 * p + h) * N_TOK + row0 + j * 4,
                  lb + (2 * p) * BM);
    }
  };
  // fallback (no zT buffer): reg-stage + b32 transpose scatter (4-way, small)
  float4 pz[2];
  auto LOADZG = [&](int gs) {
    int d0 = (gs & (KSTEPS - 1)) * BK;
    #pragma unroll
    for (int it = 0; it < 2; ++it) {
      int l = it * 256 + tid;
      pz[it] = *(const float4*)&zsrc[(size_t)(row0 + (l >> 2)) * DIM + d0 + (l & 3) * 4];
    }
  };
  auto STOREZ = [&](int b) {
    float* zb = zt + b * (BK * BM);
    #pragma unroll
    for (int it = 0; it < 2; ++it) {
      int l = it * 256 + tid;
      int zrow = l >> 2, zdg = l & 3;
      zb[(zdg * 4 + 0) * BM + zrow] = pz[it].x;
      zb[(zdg * 4 + 1) * BM + zrow] = pz[it].y;
      zb[(zdg * 4 + 2) * BM + zrow] = pz[it].z;
      zb[(zdg * 4 + 3) * BM + zrow] = pz[it].w;
    }
  };

  LOADE(0);
  if (USE_ZT) { LOADZT(0); } else { LOADZG(0); STOREZ(0); }
  __syncthreads();  // drains vmcnt -> tile 0 resident

  for (int gs = 0; gs < NSTEP; ++gs) {
    const int buf = gs & 1;
    if (gs + 1 < NSTEP) {        // prefetch into buf^1 (read-finished 1 barrier ago)
      LOADE(gs + 1);
      if (USE_ZT) LOADZT(gs + 1); else LOADZG(gs + 1);
    }

    const float* zb = zt + buf * (BK * BM);
    const float* eb = et + buf * (BK * BN);
    #pragma unroll 4
    for (int d = 0; d < BK; ++d) {
      float4 za = *(const float4*)&zb[d * BM + ty * 4];        // rows 0-3
      float4 zc = *(const float4*)&zb[d * BM + 64 + ty * 4];   // rows 4-7
      f32x2 ep[8];
      #pragma unroll
      for (int g = 0; g < 4; ++g) {
        float4 w = *(const float4*)&eb[d * BN + g * 64 + tx * 4];
        ep[2 * g + 0] = (f32x2){w.x, w.y};
        ep[2 * g + 1] = (f32x2){w.z, w.w};
      }
      f32x2 zp[4] = {(f32x2){za.x, za.y}, (f32x2){za.z, za.w},
                     (f32x2){zc.x, zc.y}, (f32x2){zc.z, zc.w}};
      #pragma unroll
      for (int ip = 0; ip < 4; ++ip) {
        #pragma unroll
        for (int jp = 0; jp < 8; ++jp) {
          pk_fma_blo(acc[2 * ip + 0][jp], zp[ip], ep[jp]);  // row 2ip   (lo z)
          pk_fma_bhi(acc[2 * ip + 1][jp], zp[ip], ep[jp]);  // row 2ip+1 (hi z)
        }
      }
    }

    // per col-tile: reference-exact d = fl(fl(S+e2) - 2*dot), strict-< argmin
    if ((gs & (KSTEPS - 1)) == KSTEPS - 1) {
      int col0c = colbase + (gs >> 4) * BN;
      float e2r[16];
      #pragma unroll
      for (int j = 0; j < 16; ++j)
        e2r[j] = e2[col0c + (j >> 2) * 64 + tx * 4 + (j & 3)];
      #pragma unroll
      for (int i = 0; i < 8; ++i) {
        #pragma unroll
        for (int j = 0; j < 16; ++j) {  // j ascending == index ascending
          float dotv = acc[i][j >> 1][j & 1];
          float t1   = __fadd_rn(Sreg[i], e2r[j]);
          float val  = __fsub_rn(t1, __fmul_rn(2.0f, dotv));
          int cidx   = col0c + (j >> 2) * 64 + tx * 4 + (j & 3);
          if (val < best[i]) { best[i] = val; bidx[i] = cidx; }
          acc[i][j >> 1][j & 1] = 0.0f;
        }
      }
    }

    if (!USE_ZT && gs + 1 < NSTEP) STOREZ(buf ^ 1);
    __syncthreads();  // one barrier/gs
  }

  // per-row argmin across 16 tx candidates, lexicographic (val, idx)
  float* redv = smem;
  int*   redi = (int*)(smem + BM * 16);
  #pragma unroll
  for (int i = 0; i < 8; ++i) {
    int r = (i >> 2) * 64 + ty * 4 + (i & 3);
    redv[r * 16 + tx] = best[i];
    redi[r * 16 + tx] = bidx[i];
  }
  __syncthreads();
  if (tid < BM) {
    float bv = redv[tid * 16];
    int   bi = redi[tid * 16];
    #pragma unroll
    for (int u = 1; u < 16; ++u) {
      float v = redv[tid * 16 + u];
      int  ii = redi[tid * 16 + u];
      if (v < bv || (v == bv && ii < bi)) { bv = v; bi = ii; }
    }
    pval[(size_t)half * N_TOK + row0 + tid] = bv;
    pidx[(size_t)half * N_TOK + row0 + tid] = bi;
  }
}

__global__ void k_out(const float* __restrict__ z, const float* __restrict__ E,
                      const float* __restrict__ ET, int useET,
                      const float* __restrict__ pval, const int* __restrict__ pidx,
                      float* __restrict__ out, float* __restrict__ counts,
                      float* __restrict__ partials) {
  int n = blockIdx.x;
  int t = threadIdx.x;
  float bv = pval[n];
  int   bi = pidx[n];
  {  // half 1 (indices all larger; strict < keeps lowest)
    float v = pval[(size_t)N_TOK + n];
    int  ii = pidx[(size_t)N_TOK + n];
    if (v < bv || (v == bv && ii < bi)) { bv = v; bi = ii; }
  }
  int idx = bi;

  float q  = useET ? ET[(size_t)idx * DIM + t]
                   : E[(size_t)t * K_EMB + idx];
  float zz = z[(size_t)n * DIM + t];
  float dd = __fsub_rn(q, zz);
  out[(size_t)n * DIM + t] = __fadd_rn(zz, dd);  // straight-through: z + (q - z)
  float sq = __fmul_rn(dd, dd);

  #pragma unroll
  for (int o = 32; o > 0; o >>= 1) sq += __shfl_down(sq, o);
  __shared__ float wsum[4];
  if ((t & 63) == 0) wsum[t >> 6] = sq;
  __syncthreads();
  if (t == 0) {
    partials[n] = ((wsum[0] + wsum[1]) + (wsum[2] + wsum[3]));
    atomicAdd(&counts[idx], 1.0f);
    out[(size_t)N_TOK * DIM + n] = (float)idx;
  }
}

__global__ void k_final(const float* __restrict__ partials,
                        const float* __restrict__ counts,
                        float* __restrict__ out) {
  __shared__ double sd[256];
  int t = threadIdx.x;
  double s = 0.0;
  for (int i = t; i < N_TOK; i += 256) s += (double)partials[i];
  sd[t] = s;
  __syncthreads();
  for (int o = 128; o > 0; o >>= 1) { if (t < o) sd[t] += sd[t + o]; __syncthreads(); }
  double totalLoss = sd[0];
  __syncthreads();
  double s2 = 0.0;
  for (int k = t; k < K_EMB; k += 256) {
    float p = counts[k] * (1.0f / (float)N_TOK);
    s2 += (double)(p * logf(p + 1e-10f));
  }
  sd[t] = s2;
  __syncthreads();
  for (int o = 128; o > 0; o >>= 1) { if (t < o) sd[t] += sd[t + o]; __syncthreads(); }
  if (t == 0) {
    const size_t base = (size_t)N_TOK * DIM + N_TOK;  // 8421376
    out[base + 0] = 0.0f;
    out[base + 1] = 0.25f * (float)(totalLoss / (double)(N_TOK * DIM));
    out[base + 2] = expf(-(float)sd[0]);
  }
}

extern "C" void kernel_launch(void* const* d_in, const int* in_sizes, int n_in,
                              void* d_out, int out_size, void* d_ws, size_t ws_size,
                              hipStream_t stream) {
  const float* z = (const float*)d_in[0];
  const float* E = (const float*)d_in[1];
  float* out = (float*)d_out;
  char* w = (char*)d_ws;
  float* S        = (float*)(w + WS_S);
  float* e2       = (float*)(w + WS_E2);
  float* pval     = (float*)(w + WS_PVAL);
  int*   pidx     = (int*)(w + WS_PIDX);
  float* counts   = (float*)(w + WS_CNT);
  float* partials = (float*)(w + WS_PART);
  float* zT       = (float*)(w + WS_ZT);
  float* ET       = (float*)(w + WS_ET);
  const int useZT = (ws_size >= (size_t)WS_END_ZT) ? 1 : 0;
  const int useET = (ws_size >= (size_t)WS_END_ET) ? 1 : 0;

  hipMemsetAsync(w + WS_CNT, 0, K_EMB * sizeof(float), stream);
  k_sumz<<<N_TOK / 256, 256, 0, stream>>>(z, S);
  k_sume<<<K_EMB / 64, 256, 0, stream>>>(E, e2);
  if (useZT)
    k_transpose_z<<<dim3(N_TOK / 32, DIM / 32), dim3(32, 8), 0, stream>>>(z, zT);
  if (useET)
    k_transpose_e<<<dim3(K_EMB / 32, DIM / 32), dim3(32, 8), 0, stream>>>(E, ET);
  if (useZT)
    k_dist<true><<<512, 256, 0, stream>>>(zT, E, S, e2, pval, pidx);
  else
    k_dist<false><<<512, 256, 0, stream>>>(z, E, S, e2, pval, pidx);
  k_out<<<N_TOK, 256, 0, stream>>>(z, E, ET, useET, pval, pidx, out, counts, partials);
  k_final<<<1, 256, 0, stream>>>(partials, counts, out);
}

// Round 7
// 1629.725 us; speedup vs baseline: 1.1347x; 1.0034x over previous
//
#include <hip/hip_runtime.h>
#include <math.h>
#include <stdint.h>

// VQ-VAE vector quantizer (inference), MI355X / gfx950.
// N=32768 tokens, D=256, K=8192 codes. f32 (no fp32 MFMA on CDNA4; bf16/MFMA
// would flip ulp-binned argmin ties -> index mismatches. VALU only, and the
// fmaf chain over d ascending is bit-exact vs the reference: absmax=0.0).
//
// Round-7: ONE change vs round 6 (1620us): pin the register-allocation window
// with amdgpu_waves_per_eu(2,2). Rounds 4/5/6 all showed VGPR_Count=124 (<128
// acc floats) and constant ~2.87e6 VALU-busy cycles/SIMD regardless of
// scalar-vs-pk inner loop => allocator budgets for 4 waves/EU (128 regs) and
// spills half the accumulator to AGPRs (accvgpr_read/write pairs ~1.8e6
// cyc/SIMD). Pinning 2 waves/EU gives the 256-reg budget; ~195 live regs fit.

#define N_TOK   32768
#define DIM     256
#define K_EMB   8192

// ---- workspace layout (bytes) ----
#define WS_S       0          // float[32768]
#define WS_E2      131072     // float[8192]
#define WS_PVAL    163840     // float[2*32768]
#define WS_PIDX    425984     // int[2*32768]
#define WS_CNT     688128     // float[8192]
#define WS_PART    720896     // float[32768]
#define WS_ZT      851968     // float[256*32768] z transposed
#define WS_END_ZT  34406400
#define WS_ET      34406400   // float[8192*256]  E transposed (k_out gather)
#define WS_END_ET  42795008

typedef __attribute__((ext_vector_type(2))) float f32x2;

// acc.lo += z.lo*e.lo ; acc.hi += z.lo*e.hi   (broadcast LOW half of src0)
__device__ __forceinline__ void pk_fma_blo(f32x2& a, f32x2 z, f32x2 e) {
  asm("v_pk_fma_f32 %0, %1, %2, %0 op_sel:[0,0,0] op_sel_hi:[0,1,1]"
      : "+v"(a) : "v"(z), "v"(e));
}
// acc.lo += z.hi*e.lo ; acc.hi += z.hi*e.hi   (broadcast HIGH half of src0)
__device__ __forceinline__ void pk_fma_bhi(f32x2& a, f32x2 z, f32x2 e) {
  asm("v_pk_fma_f32 %0, %1, %2, %0 op_sel:[1,0,0] op_sel_hi:[1,1,1]"
      : "+v"(a) : "v"(z), "v"(e));
}

__device__ __forceinline__ void gload_lds16(const float* g, float* l) {
  __builtin_amdgcn_global_load_lds(
      (const __attribute__((address_space(1))) void*)g,
      (__attribute__((address_space(3))) void*)l, 16, 0, 0);
}

__global__ void k_sumz(const float* __restrict__ z, float* __restrict__ S) {
  int t = blockIdx.x * blockDim.x + threadIdx.x;
  const float4* zp = (const float4*)(z + (size_t)t * DIM);
  float s = 0.0f;
  #pragma unroll 4
  for (int g = 0; g < DIM / 4; ++g) {
    float4 v = zp[g];
    s = __fadd_rn(s, __fmul_rn(v.x, v.x));
    s = __fadd_rn(s, __fmul_rn(v.y, v.y));
    s = __fadd_rn(s, __fmul_rn(v.z, v.z));
    s = __fadd_rn(s, __fmul_rn(v.w, v.w));
  }
  S[t] = s;
}

// e2 exact value non-critical: fl(S+e2)==S (S~256, e2<4e-6).
__global__ void k_sume(const float* __restrict__ E, float* __restrict__ e2) {
  __shared__ float part[4][64];
  int c  = threadIdx.x & 63;
  int dq = threadIdx.x >> 6;
  int col = blockIdx.x * 64 + c;
  float s = 0.0f;
  #pragma unroll 4
  for (int d = dq * 64; d < dq * 64 + 64; ++d) {
    float v = E[(size_t)d * K_EMB + col];
    s = __fadd_rn(s, __fmul_rn(v, v));
  }
  part[dq][c] = s;
  __syncthreads();
  if (threadIdx.x < 64)
    e2[blockIdx.x * 64 + threadIdx.x] =
        __fadd_rn(__fadd_rn(part[0][threadIdx.x], part[1][threadIdx.x]),
                  __fadd_rn(part[2][threadIdx.x], part[3][threadIdx.x]));
}

// z[32768][256] -> zT[256][32768], 32x32 tiles, +1-pad LDS. ~15us.
__global__ void k_transpose_z(const float* __restrict__ z, float* __restrict__ zT) {
  __shared__ float tile[32][33];
  int n0 = blockIdx.x * 32, d0 = blockIdx.y * 32;
  int lx = threadIdx.x, ly = threadIdx.y;  // 32 x 8
  #pragma unroll
  for (int r = 0; r < 32; r += 8)
    tile[ly + r][lx] = z[(size_t)(n0 + ly + r) * DIM + d0 + lx];
  __syncthreads();
  #pragma unroll
  for (int r = 0; r < 32; r += 8)
    zT[(size_t)(d0 + ly + r) * N_TOK + n0 + lx] = tile[lx][ly + r];
}

// E[256][8192] -> ET[8192][256] for k_out's coalesced row gather.
__global__ void k_transpose_e(const float* __restrict__ E, float* __restrict__ ET) {
  __shared__ float tile[32][33];
  int k0 = blockIdx.x * 32, d0 = blockIdx.y * 32;
  int lx = threadIdx.x, ly = threadIdx.y;
  #pragma unroll
  for (int r = 0; r < 32; r += 8)
    tile[ly + r][lx] = E[(size_t)(d0 + ly + r) * K_EMB + k0 + lx];
  __syncthreads();
  #pragma unroll
  for (int r = 0; r < 32; r += 8)
    ET[(size_t)(k0 + ly + r) * DIM + d0 + lx] = tile[lx][ly + r];
}

// ---- fused distance-GEMM + argmin ----
// 8x16 per-thread tile as f32x2 acc[8][8]. BM=128, BN=256, BK=16, 48KB LDS
// double-buffered, both operands staged via global_load_lds, 2 blocks/CU.
// Per d per thread: 6 b128 LDS reads + 64 pk-FMA (0 movs via op_sel).
#define BM 128
#define BN 256
#define BK 16
#define KSTEPS 16
#define NCT 16                   // 16 col-tiles x 256 = 4096 cols (half of K)
#define NSTEP (NCT * KSTEPS)     // 256

template<bool USE_ZT>
__global__
__attribute__((amdgpu_flat_work_group_size(256, 256), amdgpu_waves_per_eu(2, 2)))
void k_dist(const float* __restrict__ zsrc, const float* __restrict__ E,
            const float* __restrict__ S, const float* __restrict__ e2,
            float* __restrict__ pval, int* __restrict__ pidx) {
  __shared__ __align__(16) float smem[2 * BK * BM + 2 * BK * BN];  // 48 KB
  float* zt = smem;
  float* et = smem + 2 * BK * BM;

  const int tid = threadIdx.x;
  const int tx  = tid & 15;     // col group
  const int ty  = tid >> 4;     // row group
  const int wv  = tid >> 6;
  const int ln  = tid & 63;
  const int rowblk = blockIdx.x >> 1;
  const int half   = blockIdx.x & 1;
  const int row0    = rowblk * BM;
  const int colbase = half * (NCT * BN);

  f32x2 acc[8][8];   // acc[i][jp] = row i, cols (2jp, 2jp+1) of the 16-col strip
  #pragma unroll
  for (int i = 0; i < 8; ++i)
    #pragma unroll
    for (int jp = 0; jp < 8; ++jp) acc[i][jp] = (f32x2){0.0f, 0.0f};

  float best[8];
  int   bidx[8];
  #pragma unroll
  for (int i = 0; i < 8; ++i) { best[i] = 3.402823466e38f; bidx[i] = 0; }

  float Sreg[8];
  #pragma unroll
  for (int i = 0; i < 8; ++i)
    Sreg[i] = S[row0 + (i >> 2) * 64 + ty * 4 + (i & 3)];

  // E tile: 16 d-rows x 1KB; wave wv stages d-rows {wv,4+wv,8+wv,12+wv}
  auto LOADE = [&](int gs) {
    int ks = gs & (KSTEPS - 1), ct = gs >> 4;
    const float* gsrc = E + (size_t)(ks * BK) * K_EMB + colbase + ct * BN + ln * 4;
    float* lb = et + (gs & 1) * (BK * BN);
    #pragma unroll
    for (int it = 0; it < 4; ++it) {
      int dd = it * 4 + wv;
      gload_lds16(gsrc + (size_t)dd * K_EMB, lb + dd * BN);
    }
  };
  // zT tile: 16 d-rows x 512B; one 1KB wave-instr covers a d-row PAIR
  auto LOADZT = [&](int gs) {
    int d0 = (gs & (KSTEPS - 1)) * BK;
    float* lb = zt + (gs & 1) * (BK * BM);
    int h = ln >> 5, j = ln & 31;
    #pragma unroll
    for (int it = 0; it < 2; ++it) {
      int p = it * 4 + wv;
      gload_lds16(zsrc + (size_t)(d0 + 2 * p + h) * N_TOK + row0 + j * 4,
                  lb + (2 * p) * BM);
    }
  };
  // fallback (no zT buffer): reg-stage + b32 transpose scatter (4-way, small)
  float4 pz[2];
  auto LOADZG = [&](int gs) {
    int d0 = (gs & (KSTEPS - 1)) * BK;
    #pragma unroll
    for (int it = 0; it < 2; ++it) {
      int l = it * 256 + tid;
      pz[it] = *(const float4*)&zsrc[(size_t)(row0 + (l >> 2)) * DIM + d0 + (l & 3) * 4];
    }
  };
  auto STOREZ = [&](int b) {
    float* zb = zt + b * (BK * BM);
    #pragma unroll
    for (int it = 0; it < 2; ++it) {
      int l = it * 256 + tid;
      int zrow = l >> 2, zdg = l & 3;
      zb[(zdg * 4 + 0) * BM + zrow] = pz[it].x;
      zb[(zdg * 4 + 1) * BM + zrow] = pz[it].y;
      zb[(zdg * 4 + 2) * BM + zrow] = pz[it].z;
      zb[(zdg * 4 + 3) * BM + zrow] = pz[it].w;
    }
  };

  LOADE(0);
  if (USE_ZT) { LOADZT(0); } else { LOADZG(0); STOREZ(0); }
  __syncthreads();  // drains vmcnt -> tile 0 resident

  for (int gs = 0; gs < NSTEP; ++gs) {
    const int buf = gs & 1;
    if (gs + 1 < NSTEP) {        // prefetch into buf^1 (read-finished 1 barrier ago)
      LOADE(gs + 1);
      if (USE_ZT) LOADZT(gs + 1); else LOADZG(gs + 1);
    }

    const float* zb = zt + buf * (BK * BM);
    const float* eb = et + buf * (BK * BN);
    #pragma unroll 4
    for (int d = 0; d < BK; ++d) {
      float4 za = *(const float4*)&zb[d * BM + ty * 4];        // rows 0-3
      float4 zc = *(const float4*)&zb[d * BM + 64 + ty * 4];   // rows 4-7
      f32x2 ep[8];
      #pragma unroll
      for (int g = 0; g < 4; ++g) {
        float4 w = *(const float4*)&eb[d * BN + g * 64 + tx * 4];
        ep[2 * g + 0] = (f32x2){w.x, w.y};
        ep[2 * g + 1] = (f32x2){w.z, w.w};
      }
      f32x2 zp[4] = {(f32x2){za.x, za.y}, (f32x2){za.z, za.w},
                     (f32x2){zc.x, zc.y}, (f32x2){zc.z, zc.w}};
      #pragma unroll
      for (int ip = 0; ip < 4; ++ip) {
        #pragma unroll
        for (int jp = 0; jp < 8; ++jp) {
          pk_fma_blo(acc[2 * ip + 0][jp], zp[ip], ep[jp]);  // row 2ip   (lo z)
          pk_fma_bhi(acc[2 * ip + 1][jp], zp[ip], ep[jp]);  // row 2ip+1 (hi z)
        }
      }
    }

    // per col-tile: reference-exact d = fl(fl(S+e2) - 2*dot), strict-< argmin
    if ((gs & (KSTEPS - 1)) == KSTEPS - 1) {
      int col0c = colbase + (gs >> 4) * BN;
      float e2r[16];
      #pragma unroll
      for (int j = 0; j < 16; ++j)
        e2r[j] = e2[col0c + (j >> 2) * 64 + tx * 4 + (j & 3)];
      #pragma unroll
      for (int i = 0; i < 8; ++i) {
        #pragma unroll
        for (int j = 0; j < 16; ++j) {  // j ascending == index ascending
          float dotv = acc[i][j >> 1][j & 1];
          float t1   = __fadd_rn(Sreg[i], e2r[j]);
          float val  = __fsub_rn(t1, __fmul_rn(2.0f, dotv));
          int cidx   = col0c + (j >> 2) * 64 + tx * 4 + (j & 3);
          if (val < best[i]) { best[i] = val; bidx[i] = cidx; }
          acc[i][j >> 1][j & 1] = 0.0f;
        }
      }
    }

    if (!USE_ZT && gs + 1 < NSTEP) STOREZ(buf ^ 1);
    __syncthreads();  // one barrier/gs
  }

  // per-row argmin across 16 tx candidates, lexicographic (val, idx)
  float* redv = smem;
  int*   redi = (int*)(smem + BM * 16);
  #pragma unroll
  for (int i = 0; i < 8; ++i) {
    int r = (i >> 2) * 64 + ty * 4 + (i & 3);
    redv[r * 16 + tx] = best[i];
    redi[r * 16 + tx] = bidx[i];
  }
  __syncthreads();
  if (tid < BM) {
    float bv = redv[tid * 16];
    int   bi = redi[tid * 16];
    #pragma unroll
    for (int u = 1; u < 16; ++u) {
      float v = redv[tid * 16 + u];
      int  ii = redi[tid * 16 + u];
      if (v < bv || (v == bv && ii < bi)) { bv = v; bi = ii; }
    }
    pval[(size_t)half * N_TOK + row0 + tid] = bv;
    pidx[(size_t)half * N_TOK + row0 + tid] = bi;
  }
}

__global__ void k_out(const float* __restrict__ z, const float* __restrict__ E,
                      const float* __restrict__ ET, int useET,
                      const float* __restrict__ pval, const int* __restrict__ pidx,
                      float* __restrict__ out, float* __restrict__ counts,
                      float* __restrict__ partials) {
  int n = blockIdx.x;
  int t = threadIdx.x;
  float bv = pval[n];
  int   bi = pidx[n];
  {  // half 1 (indices all larger; strict < keeps lowest)
    float v = pval[(size_t)N_TOK + n];
    int  ii = pidx[(size_t)N_TOK + n];
    if (v < bv || (v == bv && ii < bi)) { bv = v; bi = ii; }
  }
  int idx = bi;

  float q  = useET ? ET[(size_t)idx * DIM + t]
                   : E[(size_t)t * K_EMB + idx];
  float zz = z[(size_t)n * DIM + t];
  float dd = __fsub_rn(q, zz);
  out[(size_t)n * DIM + t] = __fadd_rn(zz, dd);  // straight-through: z + (q - z)
  float sq = __fmul_rn(dd, dd);

  #pragma unroll
  for (int o = 32; o > 0; o >>= 1) sq += __shfl_down(sq, o);
  __shared__ float wsum[4];
  if ((t & 63) == 0) wsum[t >> 6] = sq;
  __syncthreads();
  if (t == 0) {
    partials[n] = ((wsum[0] + wsum[1]) + (wsum[2] + wsum[3]));
    atomicAdd(&counts[idx], 1.0f);
    out[(size_t)N_TOK * DIM + n] = (float)idx;
  }
}

__global__ void k_final(const float* __restrict__ partials,
                        const float* __restrict__ counts,
                        float* __restrict__ out) {
  __shared__ double sd[256];
  int t = threadIdx.x;
  double s = 0.0;
  for (int i = t; i < N_TOK; i += 256) s += (double)partials[i];
  sd[t] = s;
  __syncthreads();
  for (int o = 128; o > 0; o >>= 1) { if (t < o) sd[t] += sd[t + o]; __syncthreads(); }
  double totalLoss = sd[0];
  __syncthreads();
  double s2 = 0.0;
  for (int k = t; k < K_EMB; k += 256) {
    float p = counts[k] * (1.0f / (float)N_TOK);
    s2 += (double)(p * logf(p + 1e-10f));
  }
  sd[t] = s2;
  __syncthreads();
  for (int o = 128; o > 0; o >>= 1) { if (t < o) sd[t] += sd[t + o]; __syncthreads(); }
  if (t == 0) {
    const size_t base = (size_t)N_TOK * DIM + N_TOK;  // 8421376
    out[base + 0] = 0.0f;
    out[base + 1] = 0.25f * (float)(totalLoss / (double)(N_TOK * DIM));
    out[base + 2] = expf(-(float)sd[0]);
  }
}

extern "C" void kernel_launch(void* const* d_in, const int* in_sizes, int n_in,
                              void* d_out, int out_size, void* d_ws, size_t ws_size,
                              hipStream_t stream) {
  const float* z = (const float*)d_in[0];
  const float* E = (const float*)d_in[1];
  float* out = (float*)d_out;
  char* w = (char*)d_ws;
  float* S        = (float*)(w + WS_S);
  float* e2       = (float*)(w + WS_E2);
  float* pval     = (float*)(w + WS_PVAL);
  int*   pidx     = (int*)(w + WS_PIDX);
  float* counts   = (float*)(w + WS_CNT);
  float* partials = (float*)(w + WS_PART);
  float* zT       = (float*)(w + WS_ZT);
  float* ET       = (float*)(w + WS_ET);
  const int useZT = (ws_size >= (size_t)WS_END_ZT) ? 1 : 0;
  const int useET = (ws_size >= (size_t)WS_END_ET) ? 1 : 0;

  hipMemsetAsync(w + WS_CNT, 0, K_EMB * sizeof(float), stream);
  k_sumz<<<N_TOK / 256, 256, 0, stream>>>(z, S);
  k_sume<<<K_EMB / 64, 256, 0, stream>>>(E, e2);
  if (useZT)
    k_transpose_z<<<dim3(N_TOK / 32, DIM / 32), dim3(32, 8), 0, stream>>>(z, zT);
  if (useET)
    k_transpose_e<<<dim3(K_EMB / 32, DIM / 32), dim3(32, 8), 0, stream>>>(E, ET);
  if (useZT)
    k_dist<true><<<512, 256, 0, stream>>>(zT, E, S, e2, pval, pidx);
  else
    k_dist<false><<<512, 256, 0, stream>>>(z, E, S, e2, pval, pidx);
  k_out<<<N_TOK, 256, 0, stream>>>(z, E, ET, useET, pval, pidx, out, counts, partials);
  k_final<<<1, 256, 0, stream>>>(partials, counts, out);
}